// Round 3
// baseline (1909.778 us; speedup 1.0000x reference)
//
#include <hip/hip_runtime.h>
#include <hip/hip_fp16.h>
#include <cstddef>

// StackLSTM: T=64, B=128, H=256, L=2.  ops∈{0,1} => stack never pops:
// top-of-stack = h(last push step), maintained by gated update.
//
// Round-3 design: weight-stationary. 256 WGs = (bg 0..15, hg 0..15); WG owns
// batch elements bg*8..bg*8+7 and h-cols hg*16..hg*16+15 (=> 64 gate cols per
// layer). All its weights (96 KB, f16) live in LDS for the whole kernel.
// Per step: ONE 16-WG barrier per batch group (same XCD under %8 round-robin).
#define TT 64
#define BB 128
#define HH 256
#define G4 1024
#define BLK 512

// ws float-slot offsets
#define OFF_XGS    0u          // [64 t][16 hg][128 b][64 c] fp32 = 8,388,608
#define OFF_PW     8388608u    // [16 hg][3 m][64 k4][64 lc] uint2 = 393,216 slots
#define OFF_WTIH0  8781824u    // [256][1024] fp32 W_ih[0]^T (for xg) = 262,144
#define OFF_HX0    9043968u    // [2 par][16 bg][8 b][128 k2] uint = 32,768
#define OFF_HX1    9076736u    // same
#define OFF_CTR    9109504u    // 16 counters, stride 64 uints
// total ~9.11M floats = 36.4 MB

__device__ __forceinline__ float sigf(float x) { return 1.0f / (1.0f + expf(-x)); }

typedef _Float16 h2v __attribute__((ext_vector_type(2)));

__device__ __forceinline__ float dot2acc(unsigned w, unsigned h, float acc) {
#if __has_builtin(__builtin_amdgcn_fdot2)
  return __builtin_amdgcn_fdot2(__builtin_bit_cast(h2v, w),
                                __builtin_bit_cast(h2v, h), acc, false);
#else
  __half2 wv = *(__half2*)&w, hv = *(__half2*)&h;
  float2 wf = __half22float2(wv), hf = __half22float2(hv);
  return fmaf(wf.x, hf.x, fmaf(wf.y, hf.y, acc));
#endif
}

// ---------------------------------------------------------------------------
// transpose W_ih[0] [1024][256] -> [256][1024] fp32 (for xg_kernel)
// ---------------------------------------------------------------------------
__global__ void transpose1(const float* __restrict__ W_ih, float* __restrict__ ws) {
  __shared__ float tile[32][33];
  float* dst = ws + OFF_WTIH0;
  const int g0 = blockIdx.x * 32, k0 = blockIdx.y * 32;
  const int tx = threadIdx.x, ty = threadIdx.y;
#pragma unroll
  for (int i = 0; i < 32; i += 8)
    tile[ty + i][tx] = W_ih[(size_t)(g0 + ty + i) * HH + k0 + tx];
  __syncthreads();
#pragma unroll
  for (int i = 0; i < 32; i += 8)
    dst[(size_t)(k0 + ty + i) * G4 + g0 + tx] = tile[tx][ty + i];
}

// ---------------------------------------------------------------------------
// pack W_hh[0], W_ih[1], W_hh[1] as f16 into PW[hg][m][k4][lc] uint2
// gate col g = (lc>>4)*256 + hg*16 + (lc&15); uint2 = f16 x4 over k = k4*4..+3
// ---------------------------------------------------------------------------
__global__ void pack_f16(const float* __restrict__ W_ih,
                         const float* __restrict__ W_hh,
                         float* __restrict__ ws) {
  const int fid = blockIdx.x * 256 + threadIdx.x;  // [0, 196608)
  const int hg = fid / 12288;
  const int rem = fid % 12288;
  const int m = rem / 4096;
  const int k4 = (rem >> 6) & 63;
  const int lc = rem & 63;
  const int g = ((lc >> 4) << 8) + hg * 16 + (lc & 15);
  const float* src = (m == 0) ? W_hh
                   : (m == 1) ? (W_ih + (size_t)G4 * HH)
                              : (W_hh + (size_t)G4 * HH);
  const float* p = src + (size_t)g * HH + k4 * 4;
  const unsigned h0 = __half_as_ushort(__float2half(p[0]));
  const unsigned h1 = __half_as_ushort(__float2half(p[1]));
  const unsigned h2 = __half_as_ushort(__float2half(p[2]));
  const unsigned h3 = __half_as_ushort(__float2half(p[3]));
  uint2* dst = (uint2*)(ws + OFF_PW);
  dst[fid] = make_uint2(h0 | (h1 << 16), h2 | (h3 << 16));
}

// ---------------------------------------------------------------------------
// XgS[t][hg][b][c] = b_ih0[g(c,hg)] + x[t,b,:] @ W_ih0[g,:]   (fp32, exact)
// ---------------------------------------------------------------------------
__global__ void xg_kernel(const float* __restrict__ x,
                          const float* __restrict__ b_ih,
                          float* __restrict__ ws) {
  const float* __restrict__ WTih0 = ws + OFF_WTIH0;
  float* __restrict__ Xg = ws + OFF_XGS;
  const int r0 = blockIdx.x * 16;                 // 16 rows, same t
  const int g = blockIdx.y * 256 + threadIdx.x;   // gate col
  __shared__ float xs[16][HH];
  for (int i = threadIdx.x; i < 16 * HH; i += 256)
    xs[i >> 8][i & 255] = x[(size_t)(r0 + (i >> 8)) * HH + (i & 255)];
  __syncthreads();
  float acc[16];
  const float bias = b_ih[g];
#pragma unroll
  for (int r = 0; r < 16; ++r) acc[r] = bias;
  for (int k = 0; k < HH; ++k) {
    const float w = WTih0[(size_t)k * G4 + g];
#pragma unroll
    for (int r = 0; r < 16; ++r) acc[r] = fmaf(xs[r][k], w, acc[r]);
  }
  const int hg = (g >> 4) & 15;
  const int c = ((g >> 8) << 4) + (g & 15);
#pragma unroll
  for (int r = 0; r < 16; ++r) {
    const int rr = r0 + r;
    const int t = rr >> 7, b = rr & 127;
    Xg[(((size_t)t * 16 + hg) * 128 + b) * 64 + c] = acc[r];
  }
}

// ---------------------------------------------------------------------------
__global__ void zero_ctr(float* __restrict__ ws) {
  ((unsigned*)(ws + OFF_CTR))[threadIdx.x] = 0u;
}

// ---------------------------------------------------------------------------
// Sequential recurrence, weight-stationary in LDS.
// ---------------------------------------------------------------------------
__global__ void __launch_bounds__(BLK)
seq3(const float* __restrict__ b_ih,
     const float* __restrict__ b_hh,
     const int* __restrict__ ops,
     float* __restrict__ ws,
     float* __restrict__ out) {
  const int bg = blockIdx.x & 15;
  const int hg = blockIdx.x >> 4;
  const int tid = threadIdx.x;
  const int bl = tid >> 6;   // local batch element 0..7 (one wave per b)
  const int lc = tid & 63;   // local gate col 0..63

  __shared__ unsigned LW[24576];    // 96 KB: [m][k4][lc] uint2 at ((m*64+k4)*64+lc)*2
  __shared__ unsigned hp0[1024];    // [8 b][128 k2] half2 top-of-stack h, layer 0
  __shared__ unsigned hp1[1024];
  __shared__ unsigned h0c[1024];    // raw h0(t) (ungated), layer-1 input
  __shared__ float gat[512];        // [8 b][64 c]
  __shared__ int opsL[512];         // [64 t][8 b]
  __shared__ unsigned hlocu[64];    // [8 b][16 r] f16, pair-packed view

  // ---- prologue: stage weights, ops; zero state ----
  {
    const uint4* gw = (const uint4*)((const unsigned*)(ws + OFF_PW) + (size_t)hg * 24576);
    uint4* lw4 = (uint4*)LW;
    for (int i = tid; i < 6144; i += BLK) lw4[i] = gw[i];
    for (int i = tid; i < 512; i += BLK) opsL[i] = ops[(i >> 3) * BB + bg * 8 + (i & 7)];
    for (int i = tid; i < 1024; i += BLK) { hp0[i] = 0u; hp1[i] = 0u; }
  }
  const int g = ((lc >> 4) << 8) + hg * 16 + (lc & 15);
  const float bias0 = b_hh[g];                        // b_ih0 folded into Xg
  const float bias1 = b_ih[G4 + g] + b_hh[G4 + g];
  unsigned* __restrict__ Hx0 = (unsigned*)(ws + OFF_HX0);
  unsigned* __restrict__ Hx1 = (unsigned*)(ws + OFF_HX1);
  unsigned* ctr = (unsigned*)(ws + OFF_CTR) + bg * 64;
  float cp0 = 0.f, cp1 = 0.f;                         // cell state (tid<128)
  const int cb = tid >> 4, cr = tid & 15;             // cell thread mapping
  __syncthreads();

  for (int t = 0; t < TT; ++t) {
    const int par = t & 1;
    // Xg prefetch (consumed at end of L0 dots — latency hidden)
    const float xg = ws[OFF_XGS + (((size_t)t * 16 + hg) * 128 + bg * 8 + bl) * 64 + lc];

    // ---- layer 0 gates: full-K dot over LDS weights ----
    float a0 = 0.f, a1 = 0.f;
    {
      const unsigned* hb = hp0 + bl * 128;
#pragma unroll 4
      for (int k4 = 0; k4 < 64; k4 += 2) {
        const uint2 w0 = *(const uint2*)(LW + (k4 * 64 + lc) * 2);
        const uint2 h0 = *(const uint2*)(hb + k4 * 2);
        const uint2 w1 = *(const uint2*)(LW + ((k4 + 1) * 64 + lc) * 2);
        const uint2 h1 = *(const uint2*)(hb + (k4 + 1) * 2);
        a0 = dot2acc(w0.x, h0.x, a0); a0 = dot2acc(w0.y, h0.y, a0);
        a1 = dot2acc(w1.x, h1.x, a1); a1 = dot2acc(w1.y, h1.y, a1);
      }
    }
    gat[bl * 64 + lc] = a0 + a1 + bias0 + xg;
    __syncthreads();

    // ---- cell 0 ----
    if (tid < 128) {
      const float ig = gat[cb * 64 + cr],      fg = gat[cb * 64 + 16 + cr];
      const float gg = gat[cb * 64 + 32 + cr], og = gat[cb * 64 + 48 + cr];
      const float c = sigf(fg) * cp0 + sigf(ig) * tanhf(gg);
      const float h = sigf(og) * tanhf(c);
      if (opsL[t * 8 + cb]) cp0 = c;
      ((unsigned short*)hlocu)[cb * 16 + cr] = __half_as_ushort(__float2half(h));
    }
    __syncthreads();

    // ---- publish h0 (f16 pairs) ----
    if (tid < 64) {
      const int b = tid >> 3, j = tid & 7;
      Hx0[(par * 16 + bg) * 1024 + b * 128 + hg * 8 + j] = hlocu[b * 8 + j];
    }
    __syncthreads();  // drains vmcnt before the flag add

    // ---- the ONE cross-WG barrier (batch group, 16 WGs, same XCD) ----
    if (tid == 0) {
      __hip_atomic_fetch_add(ctr, 1u, __ATOMIC_RELEASE, __HIP_MEMORY_SCOPE_AGENT);
      const unsigned target = 16u * (unsigned)(t + 1);
      int spins = 0;
      while (__hip_atomic_load(ctr, __ATOMIC_ACQUIRE, __HIP_MEMORY_SCOPE_AGENT) < target) {
        __builtin_amdgcn_s_sleep(2);
        if (++spins > (1 << 22)) break;  // fail loudly (absmax) instead of hanging
      }
    }
    __syncthreads();
    __builtin_amdgcn_fence(__ATOMIC_ACQUIRE, "agent");

    // ---- merge published h0(t) and h1(t-1) ----
    {
      const unsigned* src0 = Hx0 + (par * 16 + bg) * 1024;
#pragma unroll
      for (int i = 0; i < 2; ++i) {
        const int idx = tid + i * 512;
        const unsigned v = src0[idx];
        h0c[idx] = v;
        if (opsL[t * 8 + (idx >> 7)]) hp0[idx] = v;
      }
      if (t > 0) {
        const unsigned* src1 = Hx1 + (((t - 1) & 1) * 16 + bg) * 1024;
#pragma unroll
        for (int i = 0; i < 2; ++i) {
          const int idx = tid + i * 512;
          const unsigned v = src1[idx];
          if (opsL[(t - 1) * 8 + (idx >> 7)]) hp1[idx] = v;
        }
      }
    }
    __syncthreads();

    // ---- layer 1 gates: W_ih1 @ h0c + W_hh1 @ hp1 ----
    float b0 = 0.f, b1 = 0.f;
    {
      const unsigned* hbc = h0c + bl * 128;
      const unsigned* hbp = hp1 + bl * 128;
#pragma unroll 4
      for (int k4 = 0; k4 < 64; ++k4) {
        const uint2 w1 = *(const uint2*)(LW + 8192 + (k4 * 64 + lc) * 2);
        const uint2 hc = *(const uint2*)(hbc + k4 * 2);
        const uint2 w2 = *(const uint2*)(LW + 16384 + (k4 * 64 + lc) * 2);
        const uint2 hp = *(const uint2*)(hbp + k4 * 2);
        b0 = dot2acc(w1.x, hc.x, b0); b0 = dot2acc(w1.y, hc.y, b0);
        b1 = dot2acc(w2.x, hp.x, b1); b1 = dot2acc(w2.y, hp.y, b1);
      }
    }
    gat[bl * 64 + lc] = b0 + b1 + bias1;
    __syncthreads();

    // ---- cell 1 + output ----
    if (tid < 128) {
      const float ig = gat[cb * 64 + cr],      fg = gat[cb * 64 + 16 + cr];
      const float gg = gat[cb * 64 + 32 + cr], og = gat[cb * 64 + 48 + cr];
      const float c = sigf(fg) * cp1 + sigf(ig) * tanhf(gg);
      const float h = sigf(og) * tanhf(c);
      if (opsL[t * 8 + cb]) cp1 = c;
      out[((size_t)t * BB + bg * 8 + cb) * HH + hg * 16 + cr] = h;
      ((unsigned short*)hlocu)[cb * 16 + cr] = __half_as_ushort(__float2half(h));
    }
    __syncthreads();

    // ---- publish h1 (consumed after barrier(t+1)) ----
    if (tid < 64) {
      const int b = tid >> 3, j = tid & 7;
      Hx1[(par * 16 + bg) * 1024 + b * 128 + hg * 8 + j] = hlocu[b * 8 + j];
    }
    __syncthreads();
  }
}

// ---------------------------------------------------------------------------
extern "C" void kernel_launch(void* const* d_in, const int* in_sizes, int n_in,
                              void* d_out, int out_size, void* d_ws, size_t ws_size,
                              hipStream_t stream) {
  const float* x    = (const float*)d_in[0];
  const int*   ops  = (const int*)d_in[1];
  const float* W_ih = (const float*)d_in[2];
  const float* W_hh = (const float*)d_in[3];
  const float* b_ih = (const float*)d_in[4];
  const float* b_hh = (const float*)d_in[5];
  float* out = (float*)d_out;
  float* ws  = (float*)d_ws;

  transpose1<<<dim3(32, 8), dim3(32, 8), 0, stream>>>(W_ih, ws);
  pack_f16<<<768, 256, 0, stream>>>(W_ih, W_hh, ws);
  xg_kernel<<<dim3(512, 4), 256, 0, stream>>>(x, b_ih, ws);
  zero_ctr<<<1, 1024, 0, stream>>>(ws);
  seq3<<<256, BLK, 0, stream>>>(b_ih, b_hh, ops, ws, out);
}